// Round 2
// baseline (545.030 us; speedup 1.0000x reference)
//
#include <hip/hip_runtime.h>

typedef unsigned short u16;
typedef unsigned int u32;
typedef __attribute__((ext_vector_type(8))) short short8;   // 8 bf16 MFMA frag (4 VGPRs)
typedef __attribute__((ext_vector_type(4))) float f32x4;
typedef __attribute__((ext_vector_type(2))) unsigned int u32x2;
typedef __attribute__((ext_vector_type(4))) unsigned int u32x4;

#define BB 4
#define CC 256
#define NT 4096
#define L2E 1.4426950408889634f

__device__ __forceinline__ float b2f(u16 v) {
    union { u32 u; float f; } c; c.u = ((u32)v) << 16; return c.f;
}
__device__ __forceinline__ u16 f2b(float f) {
    union { float f; u32 u; } c; c.f = f;
    u32 u = c.u;
    return (u16)((u + 0x7fffu + ((u >> 16) & 1u)) >> 16);   // RNE
}

// ---------------------------------------------------------------------------
// K0: prep — Dekker-split W=[Wq;Wk;Wv] (320x256 fp32) into wh/wl bf16 and
// pack biases into one 320-float array. Grid 20 blocks x 16 rows.
// ---------------------------------------------------------------------------
__global__ __launch_bounds__(256) void kprep(
    const float* __restrict__ Wq, const float* __restrict__ Wk,
    const float* __restrict__ Wv, const float* __restrict__ bq,
    const float* __restrict__ bk_, const float* __restrict__ bv,
    u16* __restrict__ wh, u16* __restrict__ wl, float* __restrict__ biasAll)
{
    const int bkx = blockIdx.x;          // 0..19
    const int t = threadIdx.x;
    #pragma unroll
    for (int j = 0; j < 4; ++j) {
        const int idx4 = t + 256 * j;            // 0..1023 f32x4 chunks of 16 rows
        const int row  = bkx * 16 + (idx4 >> 6); // 64 chunks per row
        const int col4 = (idx4 & 63) * 4;
        const float* src = row < 32 ? Wq + row * 256
                         : row < 64 ? Wk + (row - 32) * 256
                         :            Wv + (row - 64) * 256;
        f32x4 v = *(const f32x4*)(src + col4);
        u16 h[4], l[4];
        #pragma unroll
        for (int i = 0; i < 4; ++i) {
            h[i] = f2b(v[i]);
            l[i] = f2b(v[i] - b2f(h[i]));
        }
        u32x2 ph, pl;
        ph[0] = (u32)h[0] | ((u32)h[1] << 16); ph[1] = (u32)h[2] | ((u32)h[3] << 16);
        pl[0] = (u32)l[0] | ((u32)l[1] << 16); pl[1] = (u32)l[2] | ((u32)l[3] << 16);
        *(u32x2*)(wh + row * 256 + col4) = ph;
        *(u32x2*)(wl + row * 256 + col4) = pl;
    }
    if (t < 16) {
        const int row = bkx * 16 + t;
        biasAll[row] = row < 32 ? bq[row] : row < 64 ? bk_[row - 32] : bv[row - 64];
    }
}

// ---------------------------------------------------------------------------
// K1 v2: MFMA projections. Y(320x256) @ x(256x64-slice) per block, bf16 Dekker
// (3 MFMAs/k-step: ah*bh + al*bh + ah*bl, ~2^-16 rel). Block = 4 waves, wave w
// owns 16 n-cols; full x-slice staged fp32 in LDS once (coalesced), x-frags
// split h/l in registers (64 VGPR), W-frags streamed from L2 (wh/wl 160KB ea).
// 480 MFMAs/wave replaces the old 4096-FMA + 512-ds_read_b128 VALU GEMM
// (old kernel was LDS-pipe bound, ~51us floor; new floor = 16MB x-read).
// ---------------------------------------------------------------------------
__global__ __launch_bounds__(256, 1) void kproj(
    const float* __restrict__ x,
    const u16* __restrict__ wh, const u16* __restrict__ wl,
    const float* __restrict__ biasAll,
    u16* __restrict__ qh, u16* __restrict__ ql,
    u16* __restrict__ kh, u16* __restrict__ kl,
    u16* __restrict__ pvw)
{
    __shared__ __align__(16) float lX[256][68];   // [c][n], 69.6 KB, pad 68
    __shared__ float lbias[320];
    const int b = blockIdx.y, n0 = blockIdx.x * 64;
    const int t = threadIdx.x;
    const int lane = t & 63, wv = t >> 6;
    const int quad = lane >> 4, l16 = lane & 15;

    {   // stage x-slice [256 c][64 n] fp32, coalesced (16 lanes x 32B rows)
        const int kX = t >> 3, nn8 = (t & 7) * 8;
        const float* xrow = x + ((size_t)(b * CC + kX)) * NT + n0 + nn8;
        #pragma unroll
        for (int k0 = 0; k0 < 256; k0 += 32) {
            f32x4 xa = *(const f32x4*)(xrow + (size_t)k0 * NT);
            f32x4 xb = *(const f32x4*)(xrow + (size_t)k0 * NT + 4);
            *(f32x4*)&lX[k0 + kX][nn8]     = xa;
            *(f32x4*)&lX[k0 + kX][nn8 + 4] = xb;
        }
        lbias[t] = biasAll[t];
        if (t < 64) lbias[256 + t] = biasAll[256 + t];
    }
    __syncthreads();

    // B-frags: lane(quad,l16) elem e = x[c = s*32+quad*8+e][n = wv*16+l16]
    // (4-way bank alias on quad: 64 ds_read_b32, ~350cy — negligible)
    short8 bh[8], bl[8];
    const int coln = wv * 16 + l16;
    #pragma unroll
    for (int s = 0; s < 8; ++s) {
        #pragma unroll
        for (int e = 0; e < 8; ++e) {
            float v = lX[s * 32 + quad * 8 + e][coln];
            u16 h = f2b(v);
            bh[s][e] = (short)h;
            bl[s][e] = (short)f2b(v - b2f(h));
        }
    }

    f32x4 acc[20];
    #pragma unroll
    for (int mt = 0; mt < 20; ++mt) acc[mt] = (f32x4){0.f, 0.f, 0.f, 0.f};

    const u16* whp = wh + l16 * 256 + quad * 8;   // A-frag: row o=mt*16+l16, c-chunk
    const u16* wlp = wl + l16 * 256 + quad * 8;
    #pragma unroll
    for (int mt = 0; mt < 20; ++mt) {
        #pragma unroll
        for (int s = 0; s < 8; ++s) {
            short8 ah = *(const short8*)(whp + mt * 4096 + s * 32);
            short8 al = *(const short8*)(wlp + mt * 4096 + s * 32);
            acc[mt] = __builtin_amdgcn_mfma_f32_16x16x32_bf16(ah, bh[s], acc[mt], 0, 0, 0);
            acc[mt] = __builtin_amdgcn_mfma_f32_16x16x32_bf16(al, bh[s], acc[mt], 0, 0, 0);
            acc[mt] = __builtin_amdgcn_mfma_f32_16x16x32_bf16(ah, bl[s], acc[mt], 0, 0, 0);
        }
    }

    // epilogue: D row o = mt*16 + quad*4 + i, col n = n0 + wv*16 + l16
    const int n = n0 + wv * 16 + l16;
    #pragma unroll
    for (int mt = 0; mt < 20; ++mt) {
        u16 hv[4], lv[4];
        #pragma unroll
        for (int i = 0; i < 4; ++i) {
            const int o = mt * 16 + quad * 4 + i;
            const float val = acc[mt][i] + lbias[o];
            hv[i] = f2b(val);
            lv[i] = f2b(val - b2f(hv[i]));
        }
        if (mt < 2) {
            u32x2 ph, pl;
            ph[0] = (u32)hv[0] | ((u32)hv[1] << 16); ph[1] = (u32)hv[2] | ((u32)hv[3] << 16);
            pl[0] = (u32)lv[0] | ((u32)lv[1] << 16); pl[1] = (u32)lv[2] | ((u32)lv[3] << 16);
            const size_t idx = ((size_t)(b * NT + n)) * 32 + mt * 16 + quad * 4;
            *(u32x2*)(qh + idx) = ph;
            *(u32x2*)(ql + idx) = pl;
        } else if (mt < 4) {
            u32x2 ph, pl;
            ph[0] = (u32)hv[0] | ((u32)hv[1] << 16); ph[1] = (u32)hv[2] | ((u32)hv[3] << 16);
            pl[0] = (u32)lv[0] | ((u32)lv[1] << 16); pl[1] = (u32)lv[2] | ((u32)lv[3] << 16);
            const size_t idx = ((size_t)(b * NT + n)) * 32 + (mt - 2) * 16 + quad * 4;
            *(u32x2*)(kh + idx) = ph;
            *(u32x2*)(kl + idx) = pl;
        } else {
            #pragma unroll
            for (int i = 0; i < 4; ++i) {
                const int c = mt * 16 + quad * 4 + i - 64;
                pvw[((size_t)(b * CC + c)) * NT + n] = hv[i];
            }
        }
    }
}

// ---------------------------------------------------------------------------
// K2: energy + masked renormalized softmax -> sa (fp32, into d_out).
// (unchanged from round 1)
// ---------------------------------------------------------------------------
__global__ __launch_bounds__(256) void kattn(
    const u16* __restrict__ qh, const u16* __restrict__ ql,
    const u16* __restrict__ kh, const u16* __restrict__ kl,
    const float* __restrict__ valid, float* __restrict__ sa)
{
    __shared__ float sred[4][4][4];          // [wave][quad][i]
    const int b    = blockIdx.y;
    const int lane = threadIdx.x & 63;
    const int wv   = threadIdx.x >> 6;       // ct-split index 0..3
    const int r0   = blockIdx.x * 16;        // 16 q-rows per block
    const int quad = lane >> 4, l16 = lane & 15;
    const int ct0  = wv * 64;

    const size_t abase = ((size_t)(b * NT + r0 + l16)) * 32 + quad * 8;
    const short8 aqh = *(const short8*)(qh + abase);
    const short8 aql = *(const short8*)(ql + abase);
    const size_t kb = (size_t)b * NT * 32 + (size_t)l16 * 32 + quad * 8;
    const float* vb = valid + b * NT + l16;
    const f32x4 zero = {0.f, 0.f, 0.f, 0.f};

    float sacc[4] = {0.f, 0.f, 0.f, 0.f};
    for (int ct = ct0; ct < ct0 + 64; ++ct) {
        short8 bh = *(const short8*)(kh + kb + (size_t)ct * 512);
        short8 bl = *(const short8*)(kl + kb + (size_t)ct * 512);
        float vcol = vb[ct * 16];
        f32x4 d = __builtin_amdgcn_mfma_f32_16x16x32_bf16(aqh, bh, zero, 0, 0, 0);
        d = __builtin_amdgcn_mfma_f32_16x16x32_bf16(aql, bh, d, 0, 0, 0);
        d = __builtin_amdgcn_mfma_f32_16x16x32_bf16(aqh, bl, d, 0, 0, 0);
        #pragma unroll
        for (int i = 0; i < 4; ++i)
            sacc[i] += vcol * exp2f(fminf(d[i], 60.f) * L2E);
    }
    #pragma unroll
    for (int i = 0; i < 4; ++i) {
        #pragma unroll
        for (int off = 1; off < 16; off <<= 1)
            sacc[i] += __shfl_xor(sacc[i], off, 64);
    }
    if (l16 == 0) {
        #pragma unroll
        for (int i = 0; i < 4; ++i) sred[wv][quad][i] = sacc[i];
    }
    __syncthreads();
    float inv[4];
    #pragma unroll
    for (int i = 0; i < 4; ++i)
        inv[i] = 1.0f / (sred[0][quad][i] + sred[1][quad][i] +
                         sred[2][quad][i] + sred[3][quad][i]);

    for (int ct = ct0; ct < ct0 + 64; ++ct) {
        short8 bh = *(const short8*)(kh + kb + (size_t)ct * 512);
        short8 bl = *(const short8*)(kl + kb + (size_t)ct * 512);
        float vcol = vb[ct * 16];
        f32x4 d = __builtin_amdgcn_mfma_f32_16x16x32_bf16(aqh, bh, zero, 0, 0, 0);
        d = __builtin_amdgcn_mfma_f32_16x16x32_bf16(aql, bh, d, 0, 0, 0);
        d = __builtin_amdgcn_mfma_f32_16x16x32_bf16(aqh, bl, d, 0, 0, 0);
        #pragma unroll
        for (int i = 0; i < 4; ++i) {
            float val = vcol * exp2f(fminf(d[i], 60.f) * L2E) * inv[i];
            sa[((size_t)(b * NT + r0 + quad * 4 + i)) * NT + ct * 16 + l16] = val;
        }
    }
}

// ---------------------------------------------------------------------------
// K3: out[b,c,m] = gamma * sum_n pv[c,n]*sa[m,n] + x[b,c,m]  (fp32 I/O).
// (unchanged from round 1: k-step 128, dbuf swizzled LDS, reg-staged prefetch,
// raw s_barrier + lgkmcnt(0), prefetch vmcnt in flight across barriers)
// ---------------------------------------------------------------------------
#define KOUT_BODY(CUR, T, NXA, NXB, FTA, FTB)                                  \
  {                                                                            \
    if ((T) + 2 < 32) {                                                        \
      FTA = *(const f32x4*)(sap + (size_t)((T) + 2) * 128);                    \
      FTB = *(const f32x4*)(sap + (size_t)((T) + 2) * 128 + 4);                \
    }                                                                          \
    if ((T) + 1 < 32) {                                                        \
      u32 w0 = (u32)f2b(NXA[0]) | ((u32)f2b(NXA[1]) << 16);                    \
      u32 w1 = (u32)f2b(NXA[2]) | ((u32)f2b(NXA[3]) << 16);                    \
      u32 w2 = (u32)f2b(NXB[0]) | ((u32)f2b(NXB[1]) << 16);                    \
      u32 w3 = (u32)f2b(NXB[2]) | ((u32)f2b(NXB[3]) << 16);                    \
      u32x4 pk = {w0, w1, w2, w3};                                             \
      *(u32x4*)(lbw + ((((T) + 1) & 1) * 8192)) = pk;                          \
    }                                                                          \
    const char* lb = lbr + (CUR) * 8192;                                       \
    _Pragma("unroll")                                                          \
    for (int kk = 0; kk < 128; kk += 32) {                                     \
      short8 a0 = *(const short8*)(a0p + (size_t)(T) * 128 + kk);              \
      short8 a1 = *(const short8*)(a1p + (size_t)(T) * 128 + kk);              \
      const int kby = (((kk + quad * 8) * 2) ^ swz);                           \
      short8 b0 = *(const short8*)(lb + l16 * 256 + kby);                      \
      short8 b1 = *(const short8*)(lb + (16 + l16) * 256 + kby);               \
      acc00 = __builtin_amdgcn_mfma_f32_16x16x32_bf16(a0, b0, acc00, 0, 0, 0); \
      acc01 = __builtin_amdgcn_mfma_f32_16x16x32_bf16(a0, b1, acc01, 0, 0, 0); \
      acc10 = __builtin_amdgcn_mfma_f32_16x16x32_bf16(a1, b0, acc10, 0, 0, 0); \
      acc11 = __builtin_amdgcn_mfma_f32_16x16x32_bf16(a1, b1, acc11, 0, 0, 0); \
    }                                                                          \
    asm volatile("s_waitcnt lgkmcnt(0)" ::: "memory");                         \
    __builtin_amdgcn_sched_barrier(0);                                         \
    __builtin_amdgcn_s_barrier();                                              \
    __builtin_amdgcn_sched_barrier(0);                                         \
  }

__global__ __launch_bounds__(512) void kout(
    const u16* __restrict__ pvw, const float* __restrict__ sa,
    const float* __restrict__ x, const float* __restrict__ gamma,
    float* __restrict__ outp)
{
    __shared__ __align__(16) u16 lB[2][32][128];   // 2 x 8 KB, swizzled
    const int b    = blockIdx.y;
    const int m0   = blockIdx.x * 32;
    const int t    = threadIdx.x;
    const int lane = t & 63;
    const int wv   = t >> 6;
    const int c0   = wv * 32;
    const int quad = lane >> 4, l16 = lane & 15;
    const int swz  = (l16 & 7) << 4;

    const u16* a0p = pvw + ((size_t)(b * CC + c0 + l16)) * NT + quad * 8;
    const u16* a1p = a0p + (size_t)16 * NT;
    const int sm = t >> 4, sk = (t & 15) * 8;
    const float* sap = sa + ((size_t)(b * NT + m0 + sm)) * NT + sk;
    char* lbw = ((char*)&lB[0][0][0]) + sm * 256 + ((sk * 2) ^ ((sm & 7) << 4));
    const char* lbr = (const char*)&lB[0][0][0];

    f32x4 acc00 = {0,0,0,0}, acc01 = {0,0,0,0}, acc10 = {0,0,0,0}, acc11 = {0,0,0,0};

    f32x4 pA = *(const f32x4*)(sap);
    f32x4 pB = *(const f32x4*)(sap + 4);
    f32x4 nA = *(const f32x4*)(sap + 128);
    f32x4 nB = *(const f32x4*)(sap + 132);
    {
        u32 w0 = (u32)f2b(pA[0]) | ((u32)f2b(pA[1]) << 16);
        u32 w1 = (u32)f2b(pA[2]) | ((u32)f2b(pA[3]) << 16);
        u32 w2 = (u32)f2b(pB[0]) | ((u32)f2b(pB[1]) << 16);
        u32 w3 = (u32)f2b(pB[2]) | ((u32)f2b(pB[3]) << 16);
        u32x4 pk = {w0, w1, w2, w3};
        *(u32x4*)(lbw) = pk;
    }
    asm volatile("s_waitcnt lgkmcnt(0)" ::: "memory");
    __builtin_amdgcn_sched_barrier(0);
    __builtin_amdgcn_s_barrier();
    __builtin_amdgcn_sched_barrier(0);

    f32x4 fA, fB;
    for (int tt = 0; tt < 32; tt += 2) {
        KOUT_BODY(0, tt,     nA, nB, fA, fB)
        KOUT_BODY(1, tt + 1, fA, fB, nA, nB)
    }

    const float g = gamma[0];
    #pragma unroll
    for (int ai = 0; ai < 2; ++ai) {
        #pragma unroll
        for (int bi = 0; bi < 2; ++bi) {
            f32x4 acc = (ai == 0) ? ((bi == 0) ? acc00 : acc01)
                                  : ((bi == 0) ? acc10 : acc11);
            #pragma unroll
            for (int i = 0; i < 4; ++i) {
                const int c = c0 + ai * 16 + quad * 4 + i;
                const int m = m0 + bi * 16 + l16;
                const size_t idx = ((size_t)(b * CC + c)) * NT + m;
                outp[idx] = g * acc[i] + x[idx];
            }
        }
    }
}

extern "C" void kernel_launch(void* const* d_in, const int* in_sizes, int n_in,
                              void* d_out, int out_size, void* d_ws, size_t ws_size,
                              hipStream_t stream)
{
    const float* x     = (const float*)d_in[0];
    const float* valid = (const float*)d_in[1];
    const float* Wq    = (const float*)d_in[2];
    const float* bq    = (const float*)d_in[3];
    const float* Wk    = (const float*)d_in[4];
    const float* bk    = (const float*)d_in[5];
    const float* Wv    = (const float*)d_in[6];
    const float* bv    = (const float*)d_in[7];
    const float* gamma = (const float*)d_in[8];

    float* outp = (float*)d_out;
    float* sa   = outp + (size_t)BB * CC * NT;      // output chunk 1 [B][N][N] fp32

    u16* qh  = (u16*)d_ws;                          // [B][N][32] bf16, 1 MB each
    u16* ql  = qh + (size_t)BB * NT * 32;
    u16* kh  = ql + (size_t)BB * NT * 32;
    u16* kl  = kh + (size_t)BB * NT * 32;
    u16* pvw = kl + (size_t)BB * NT * 32;           // [B][C][N] bf16, 8 MB
    u16* wh  = pvw + (size_t)BB * CC * NT;          // 320x256 bf16, 160 KB
    u16* wl  = wh + 320 * 256;
    float* biasAll = (float*)(wl + 320 * 256);      // 320 fp32

    kprep<<<dim3(20), 256, 0, stream>>>(Wq, Wk, Wv, bq, bk, bv, wh, wl, biasAll);
    kproj<<<dim3(64, BB), 256, 0, stream>>>(x, wh, wl, biasAll,
                                            qh, ql, kh, kl, pvw);
    kattn<<<dim3(256, BB), 256, 0, stream>>>(qh, ql, kh, kl, valid, sa);
    kout<<<dim3(128, BB), 512, 0, stream>>>(pvw, sa, x, gamma, outp);
}